// Round 1
// baseline (582.058 us; speedup 1.0000x reference)
//
#include <hip/hip_runtime.h>
#include <math.h>

// Problem constants (from reference)
constexpr int Bsz = 16, Nn = 1024, Cc = 16, Ss = 8;
constexpr int TD = 128, KD = 128, Dd = 256, Oo = 256;
constexpr int BN = Bsz * Nn;            // 16384 nodes total
constexpr int BQ = 16;                  // nodes per block

// ---------------------------------------------------------------------------
// Kernel 1: fused embeddings + parent projection
// parent[g][o] = b[o] + sum_k emb[g][k] * Wp[k][o]
// emb = concat(type_table[node_type], sum_s token_table[node_tokens[s]])
// ---------------------------------------------------------------------------
__global__ __launch_bounds__(256) void emb_parent_kernel(
    const int* __restrict__ node_type, const int* __restrict__ node_tokens,
    const float* __restrict__ type_table, const float* __restrict__ token_table,
    const float* __restrict__ Wp, const float* __restrict__ bp,
    float* __restrict__ out)
{
    __shared__ float emb[BQ][256];
    const int tid = threadIdx.x;
    const int g0 = blockIdx.x * BQ;

    // phase 1: build emb tile [BQ][256] in LDS
    for (int r = 0; r < BQ; ++r) {
        const int g = g0 + r;
        float v;
        if (tid < 128) {
            v = type_table[node_type[g] * 128 + tid];
        } else {
            const int dd = tid - 128;
            float s = 0.f;
            #pragma unroll
            for (int si = 0; si < Ss; ++si)
                s += token_table[node_tokens[g * Ss + si] * 128 + dd];
            v = s;
        }
        emb[r][tid] = v;
    }
    __syncthreads();

    // phase 2: GEMM  [BQ x 256] @ [256 x 256]
    const int o = tid;
    float acc[BQ];
    const float bias = bp[o];
    #pragma unroll
    for (int r = 0; r < BQ; ++r) acc[r] = bias;

    for (int k = 0; k < 256; k += 4) {
        const float w0 = Wp[(k + 0) * 256 + o];
        const float w1 = Wp[(k + 1) * 256 + o];
        const float w2 = Wp[(k + 2) * 256 + o];
        const float w3 = Wp[(k + 3) * 256 + o];
        #pragma unroll
        for (int r = 0; r < BQ; ++r) {
            const float4 mv = *reinterpret_cast<const float4*>(&emb[r][k]);
            float a = acc[r];
            a = fmaf(mv.x, w0, a);
            a = fmaf(mv.y, w1, a);
            a = fmaf(mv.z, w2, a);
            a = fmaf(mv.w, w3, a);
            acc[r] = a;
        }
    }
    for (int r = 0; r < BQ; ++r) out[(size_t)(g0 + r) * 256 + o] = acc[r];
}

// ---------------------------------------------------------------------------
// Kernel 2: one tree-conv layer
// mixed[n][0][:] = nodes[n]; mixed[n][1] = sum_c eta_r[c]*child_c; mixed[n][2] likewise
// out[n][o] = tanh( sum_{k<768} mixed[n][k] * W[k][o] + bias[o] )
// ---------------------------------------------------------------------------
__global__ __launch_bounds__(256) void conv_kernel(
    const float* __restrict__ in_nodes,
    const int* __restrict__ children_index,
    const float* __restrict__ W,      // [3*256][256]
    const float* __restrict__ bias,   // [256]
    float* __restrict__ out_nodes)
{
    __shared__ float mixed[BQ][768];
    __shared__ int   idxs[BQ][Cc];
    __shared__ float etar[BQ][Cc];
    __shared__ float etal[BQ][Cc];

    const int tid = threadIdx.x;
    const int g0 = blockIdx.x * BQ;
    const int b  = g0 >> 10;                       // batch index (N=1024)
    const float* inb = in_nodes + (size_t)b * Nn * 256;

    // children indices: 16 nodes x 16 children = 256
    idxs[tid >> 4][tid & 15] = children_index[(size_t)g0 * Cc + tid];
    __syncthreads();

    // TBCNN positional coefficients (with the reference's "singles" quirk)
    {
        const int r = tid >> 4, c = tid & 15;
        int ns = 0;
        #pragma unroll
        for (int j = 0; j < Cc; ++j) ns += (idxs[r][j] > 0) ? 1 : 0;
        const bool cm = idxs[r][c] > 0;
        float er;
        if (ns == 1) {
            er = (c == 0) ? 0.5f : 0.f;           // singles: slot 1 overall == child slot 0
        } else {
            const float denom = (float)((ns - 1 > 1) ? (ns - 1) : 1);
            er = cm ? (float)c / denom : 0.f;
        }
        const float el = (1.f - er) * (cm ? 1.f : 0.f);
        etar[r][c] = er;
        etal[r][c] = el;
    }
    __syncthreads();

    // mixed tile: gather children, apply coefficients
    for (int r = 0; r < BQ; ++r) {
        const int dd = tid;
        const float m0 = in_nodes[(size_t)(g0 + r) * 256 + dd];
        float m1 = 0.f, m2 = 0.f;
        #pragma unroll
        for (int c = 0; c < Cc; ++c) {
            const int ci = idxs[r][c];
            if (ci > 0) {                          // index 0 => zero vector (padding)
                const float v = inb[(size_t)ci * 256 + dd];
                m1 = fmaf(etar[r][c], v, m1);
                m2 = fmaf(etal[r][c], v, m2);
            }
        }
        mixed[r][dd]       = m0;
        mixed[r][256 + dd] = m1;
        mixed[r][512 + dd] = m2;
    }
    __syncthreads();

    // GEMM [BQ x 768] @ [768 x 256] + tanh
    const int o = tid;
    float acc[BQ];
    const float bv = bias[o];
    #pragma unroll
    for (int r = 0; r < BQ; ++r) acc[r] = bv;

    for (int k = 0; k < 768; k += 4) {
        const float w0 = W[(k + 0) * 256 + o];
        const float w1 = W[(k + 1) * 256 + o];
        const float w2 = W[(k + 2) * 256 + o];
        const float w3 = W[(k + 3) * 256 + o];
        #pragma unroll
        for (int r = 0; r < BQ; ++r) {
            const float4 mv = *reinterpret_cast<const float4*>(&mixed[r][k]);
            float a = acc[r];
            a = fmaf(mv.x, w0, a);
            a = fmaf(mv.y, w1, a);
            a = fmaf(mv.z, w2, a);
            a = fmaf(mv.w, w3, a);
            acc[r] = a;
        }
    }
    for (int r = 0; r < BQ; ++r)
        out_nodes[(size_t)(g0 + r) * 256 + o] = tanhf(acc[r]);
}

// ---------------------------------------------------------------------------
// Kernel 3: attention score -> masked sigmoid weight per node
// ---------------------------------------------------------------------------
__global__ __launch_bounds__(256) void score_kernel(
    const float* __restrict__ nodes, const int* __restrict__ node_type,
    const float* __restrict__ attn_a, float* __restrict__ wmask)
{
    const int tid  = threadIdx.x;
    const int lane = tid & 63, wid = tid >> 6;
    const int g = blockIdx.x * 4 + wid;
    const float* row = nodes + (size_t)g * 256;
    float s = 0.f;
    #pragma unroll
    for (int j = 0; j < 4; ++j)
        s = fmaf(row[lane + 64 * j], attn_a[lane + 64 * j], s);
    #pragma unroll
    for (int off = 32; off > 0; off >>= 1) s += __shfl_down(s, off, 64);
    if (lane == 0) {
        float wm = 0.f;
        if (node_type[g] != 0) wm = 1.f / (1.f + expf(-s));
        wmask[g] = wm;
    }
}

// ---------------------------------------------------------------------------
// Kernel 4/5: masked weighted mean over N (two-stage, deterministic)
// ---------------------------------------------------------------------------
__global__ __launch_bounds__(256) void partial_kernel(
    const float* __restrict__ nodes, const float* __restrict__ wmask,
    float* __restrict__ partial)     // [128][256]
{
    const int blk = blockIdx.x;           // 0..127
    const int b = blk >> 3, chunk = blk & 7;
    const int o = threadIdx.x;
    const int n0 = chunk * 128;
    const float* base = nodes + ((size_t)b * Nn + n0) * 256;
    const float* wm   = wmask + b * Nn + n0;
    float acc = 0.f;
    for (int n = 0; n < 128; ++n) acc = fmaf(base[(size_t)n * 256 + o], wm[n], acc);
    partial[blk * 256 + o] = acc;
}

__global__ __launch_bounds__(256) void final_kernel(
    const float* __restrict__ partial, float* __restrict__ code)
{
    const int i = blockIdx.x * 256 + threadIdx.x;  // 0..4095
    const int b = i >> 8, o = i & 255;
    float acc = 0.f;
    #pragma unroll
    for (int c = 0; c < 8; ++c) acc += partial[(b * 8 + c) * 256 + o];
    code[i] = acc * (1.f / 1024.f);
}

// ---------------------------------------------------------------------------
extern "C" void kernel_launch(void* const* d_in, const int* in_sizes, int n_in,
                              void* d_out, int out_size, void* d_ws, size_t ws_size,
                              hipStream_t stream)
{
    const int*   node_type   = (const int*)d_in[0];
    const int*   node_tokens = (const int*)d_in[1];
    const int*   children    = (const int*)d_in[2];
    const float* type_table  = (const float*)d_in[3];
    const float* token_table = (const float*)d_in[4];
    const float* Wp          = (const float*)d_in[5];
    const float* bp          = (const float*)d_in[6];
    const float* conv_w      = (const float*)d_in[7];
    const float* conv_b      = (const float*)d_in[8];
    const float* attn_a      = (const float*)d_in[9];

    float* out    = (float*)d_out;
    float* code   = out;                  // [B*O] = 4096
    float* nodesA = out + 4096;           // [BN*256]  (ping buffer lives in d_out)

    float* ws      = (float*)d_ws;
    float* nodesB  = ws;                  // [BN*256]
    float* wmask   = ws + (size_t)BN * 256;   // [BN]
    float* partial = wmask + BN;          // [128*256]

    emb_parent_kernel<<<BN / BQ, 256, 0, stream>>>(
        node_type, node_tokens, type_table, token_table, Wp, bp, nodesA);

    conv_kernel<<<BN / BQ, 256, 0, stream>>>(
        nodesA, children, conv_w, conv_b, nodesB);

    conv_kernel<<<BN / BQ, 256, 0, stream>>>(
        nodesB, children, conv_w + 3 * 256 * 256, conv_b + 256, nodesA);

    score_kernel<<<BN / 4, 256, 0, stream>>>(nodesA, node_type, attn_a, wmask);

    partial_kernel<<<128, 256, 0, stream>>>(nodesA, wmask, partial);

    final_kernel<<<16, 256, 0, stream>>>(partial, code);
}

// Round 3
// 482.456 us; speedup vs baseline: 1.2064x; 1.2064x over previous
//
#include <hip/hip_runtime.h>
#include <math.h>

// Problem constants (from reference)
constexpr int Bsz = 16, Nn = 1024, Cc = 16, Ss = 8;
constexpr int BN = Bsz * Nn;            // 16384 nodes total
constexpr int BQ = 16;                  // nodes per block (emb kernel)
constexpr int CQ = 32;                  // nodes per block (conv kernel)

typedef __attribute__((ext_vector_type(8))) short bf16x8;
typedef __attribute__((ext_vector_type(4))) float f32x4;

__device__ inline unsigned short f2bf_rne(float x) {
    unsigned u = __builtin_bit_cast(unsigned, x);
    unsigned r = (u + 0x7FFFu + ((u >> 16) & 1u)) >> 16;
    return (unsigned short)r;
}
__device__ inline float bf2f(unsigned short h) {
    unsigned u = ((unsigned)h) << 16;
    return __builtin_bit_cast(float, u);
}

// ---------------------------------------------------------------------------
// Kernel 0: pack conv weights into MFMA-fragment-major hi/lo bf16.
// dst[((kb*4+g)*256+col)*8+i] = W[(kb*32+g*8+i)*256+col],  kb<24, g<4
// ---------------------------------------------------------------------------
__global__ __launch_bounds__(256) void pack_w_kernel(
    const float* __restrict__ conv_w,          // [2][768][256]
    unsigned short* __restrict__ whi, unsigned short* __restrict__ wlo)
{
    const int t = blockIdx.x * 256 + threadIdx.x;    // 0..49151
    const int col = t & 255;
    const int gg  = (t >> 8) & 3;
    const int kb  = (t >> 10) % 24;
    const int l   = t / (24 * 4 * 256);
    const float* W = conv_w + (size_t)l * 768 * 256;
    const size_t dst = (size_t)t * 8;
    #pragma unroll
    for (int i = 0; i < 8; ++i) {
        const float x = W[(size_t)(kb * 32 + gg * 8 + i) * 256 + col];
        const unsigned short h = f2bf_rne(x);
        whi[dst + i] = h;
        wlo[dst + i] = f2bf_rne(x - bf2f(h));
    }
}

// ---------------------------------------------------------------------------
// Kernel 1: fused embeddings + parent projection (fp32, unchanged)
// ---------------------------------------------------------------------------
__global__ __launch_bounds__(256) void emb_parent_kernel(
    const int* __restrict__ node_type, const int* __restrict__ node_tokens,
    const float* __restrict__ type_table, const float* __restrict__ token_table,
    const float* __restrict__ Wp, const float* __restrict__ bp,
    float* __restrict__ out)
{
    __shared__ float emb[BQ][256];
    const int tid = threadIdx.x;
    const int g0 = blockIdx.x * BQ;

    for (int r = 0; r < BQ; ++r) {
        const int g = g0 + r;
        float v;
        if (tid < 128) {
            v = type_table[node_type[g] * 128 + tid];
        } else {
            const int dd = tid - 128;
            float s = 0.f;
            #pragma unroll
            for (int si = 0; si < Ss; ++si)
                s += token_table[node_tokens[g * Ss + si] * 128 + dd];
            v = s;
        }
        emb[r][tid] = v;
    }
    __syncthreads();

    const int o = tid;
    float acc[BQ];
    const float bias = bp[o];
    #pragma unroll
    for (int r = 0; r < BQ; ++r) acc[r] = bias;

    for (int k = 0; k < 256; k += 4) {
        const float w0 = Wp[(k + 0) * 256 + o];
        const float w1 = Wp[(k + 1) * 256 + o];
        const float w2 = Wp[(k + 2) * 256 + o];
        const float w3 = Wp[(k + 3) * 256 + o];
        #pragma unroll
        for (int r = 0; r < BQ; ++r) {
            const float4 mv = *reinterpret_cast<const float4*>(&emb[r][k]);
            float a = acc[r];
            a = fmaf(mv.x, w0, a);
            a = fmaf(mv.y, w1, a);
            a = fmaf(mv.z, w2, a);
            a = fmaf(mv.w, w3, a);
            acc[r] = a;
        }
    }
    for (int r = 0; r < BQ; ++r) out[(size_t)(g0 + r) * 256 + o] = acc[r];
}

// ---------------------------------------------------------------------------
// Kernel 2: tree-conv layer with split-bf16 MFMA
//   mixed (fp32) -> hi/lo bf16 in LDS; GEMM [32 x 768]@[768 x 256] via
//   3x v_mfma_f32_16x16x32_bf16 per logical fragment; + bias + tanh.
// 8 waves: wave w covers rows 16*(w>>2), cols 64*(w&3).
// ---------------------------------------------------------------------------
__global__ __launch_bounds__(512) void conv_mfma_kernel(
    const float* __restrict__ in_nodes,
    const int* __restrict__ children_index,
    const unsigned short* __restrict__ whi,   // layer offset pre-applied
    const unsigned short* __restrict__ wlo,
    const float* __restrict__ bias,           // [256]
    float* __restrict__ out_nodes)
{
    constexpr int AP = 776;                   // padded k-stride (bf16 elems)
    __shared__ unsigned short Ahi[CQ][AP];
    __shared__ unsigned short Alo[CQ][AP];
    __shared__ int   idxs[CQ][Cc];
    __shared__ float etar[CQ][Cc];
    __shared__ float etal[CQ][Cc];

    const int tid = threadIdx.x;
    const int g0 = blockIdx.x * CQ;
    const int b  = g0 >> 10;
    const float* inb = in_nodes + (size_t)b * Nn * 256;

    // phase 1: children indices + TBCNN coefficients (one (r,c) per thread)
    {
        const int r = tid >> 4, c = tid & 15;
        idxs[r][c] = children_index[(size_t)(g0 + r) * Cc + c];
    }
    __syncthreads();
    {
        const int r = tid >> 4, c = tid & 15;
        int ns = 0;
        #pragma unroll
        for (int j = 0; j < Cc; ++j) ns += (idxs[r][j] > 0) ? 1 : 0;
        const bool cm = idxs[r][c] > 0;
        float er;
        if (ns == 1) {
            er = (c == 0) ? 0.5f : 0.f;       // reference's "singles" quirk
        } else {
            const float denom = (float)((ns - 1 > 1) ? (ns - 1) : 1);
            er = cm ? (float)c / denom : 0.f;
        }
        etar[r][c] = er;
        etal[r][c] = (1.f - er) * (cm ? 1.f : 0.f);
    }
    __syncthreads();

    // phase 2: gather + mix -> hi/lo bf16 LDS tile [32][768]
    {
        const int dd = tid & 255;
        const int r0 = (tid >> 8) * 16;
        for (int rr = 0; rr < 16; ++rr) {
            const int r = r0 + rr;
            const float m0 = in_nodes[(size_t)(g0 + r) * 256 + dd];
            float m1 = 0.f, m2 = 0.f;
            #pragma unroll
            for (int c = 0; c < Cc; ++c) {
                const int ci = idxs[r][c];
                if (ci > 0) {                  // index 0 => zero vector
                    const float v = inb[(size_t)ci * 256 + dd];
                    m1 = fmaf(etar[r][c], v, m1);
                    m2 = fmaf(etal[r][c], v, m2);
                }
            }
            const float ms[3] = {m0, m1, m2};
            #pragma unroll
            for (int s = 0; s < 3; ++s) {
                const unsigned short h = f2bf_rne(ms[s]);
                Ahi[r][s * 256 + dd] = h;
                Alo[r][s * 256 + dd] = f2bf_rne(ms[s] - bf2f(h));
            }
        }
    }
    __syncthreads();

    // phase 3: MFMA GEMM
    const int lane = tid & 63;
    const int w    = tid >> 6;
    const int rowg = (w >> 2) * 16;
    const int colg = (w & 3) * 64;
    const int rr   = lane & 15;               // A row in group / B,D col
    const int g    = lane >> 4;               // k-subgroup

    f32x4 acc[4];
    #pragma unroll
    for (int f = 0; f < 4; ++f) acc[f] = (f32x4){0.f, 0.f, 0.f, 0.f};

    for (int kb = 0; kb < 24; ++kb) {
        const int k0 = kb * 32 + g * 8;
        const bf16x8 ah = *reinterpret_cast<const bf16x8*>(&Ahi[rowg + rr][k0]);
        const bf16x8 al = *reinterpret_cast<const bf16x8*>(&Alo[rowg + rr][k0]);
        #pragma unroll
        for (int f = 0; f < 4; ++f) {
            const int col = colg + f * 16 + rr;
            const size_t off = ((size_t)((kb * 4 + g) * 256 + col)) * 8;
            const bf16x8 bh = *reinterpret_cast<const bf16x8*>(&whi[off]);
            const bf16x8 bl = *reinterpret_cast<const bf16x8*>(&wlo[off]);
            acc[f] = __builtin_amdgcn_mfma_f32_16x16x32_bf16(ah, bh, acc[f], 0, 0, 0);
            acc[f] = __builtin_amdgcn_mfma_f32_16x16x32_bf16(ah, bl, acc[f], 0, 0, 0);
            acc[f] = __builtin_amdgcn_mfma_f32_16x16x32_bf16(al, bh, acc[f], 0, 0, 0);
        }
    }

    // epilogue: D row = g*4+i, col = colg + f*16 + rr
    #pragma unroll
    for (int f = 0; f < 4; ++f) {
        const int col = colg + f * 16 + rr;
        const float bv = bias[col];
        #pragma unroll
        for (int i = 0; i < 4; ++i) {
            const int row = rowg + g * 4 + i;
            out_nodes[(size_t)(g0 + row) * 256 + col] = tanhf(acc[f][i] + bv);
        }
    }
}

// ---------------------------------------------------------------------------
// Kernel 3: attention score -> masked sigmoid weight per node
// ---------------------------------------------------------------------------
__global__ __launch_bounds__(256) void score_kernel(
    const float* __restrict__ nodes, const int* __restrict__ node_type,
    const float* __restrict__ attn_a, float* __restrict__ wmask)
{
    const int tid  = threadIdx.x;
    const int lane = tid & 63, wid = tid >> 6;
    const int g = blockIdx.x * 4 + wid;
    const float* row = nodes + (size_t)g * 256;
    float s = 0.f;
    #pragma unroll
    for (int j = 0; j < 4; ++j)
        s = fmaf(row[lane + 64 * j], attn_a[lane + 64 * j], s);
    #pragma unroll
    for (int off = 32; off > 0; off >>= 1) s += __shfl_down(s, off, 64);
    if (lane == 0) {
        float wm = 0.f;
        if (node_type[g] != 0) wm = 1.f / (1.f + expf(-s));
        wmask[g] = wm;
    }
}

// ---------------------------------------------------------------------------
// Kernel 4/5: masked weighted mean over N (two-stage, deterministic)
// ---------------------------------------------------------------------------
__global__ __launch_bounds__(256) void partial_kernel(
    const float* __restrict__ nodes, const float* __restrict__ wmask,
    float* __restrict__ partial)     // [128][256]
{
    const int blk = blockIdx.x;           // 0..127
    const int b = blk >> 3, chunk = blk & 7;
    const int o = threadIdx.x;
    const int n0 = chunk * 128;
    const float* base = nodes + ((size_t)b * Nn + n0) * 256;
    const float* wm   = wmask + b * Nn + n0;
    float acc = 0.f;
    for (int n = 0; n < 128; ++n) acc = fmaf(base[(size_t)n * 256 + o], wm[n], acc);
    partial[blk * 256 + o] = acc;
}

__global__ __launch_bounds__(256) void final_kernel(
    const float* __restrict__ partial, float* __restrict__ code)
{
    const int i = blockIdx.x * 256 + threadIdx.x;  // 0..4095
    const int b = i >> 8, o = i & 255;
    float acc = 0.f;
    #pragma unroll
    for (int c = 0; c < 8; ++c) acc += partial[(b * 8 + c) * 256 + o];
    code[i] = acc * (1.f / 1024.f);
}

// ---------------------------------------------------------------------------
extern "C" void kernel_launch(void* const* d_in, const int* in_sizes, int n_in,
                              void* d_out, int out_size, void* d_ws, size_t ws_size,
                              hipStream_t stream)
{
    const int*   node_type   = (const int*)d_in[0];
    const int*   node_tokens = (const int*)d_in[1];
    const int*   children    = (const int*)d_in[2];
    const float* type_table  = (const float*)d_in[3];
    const float* token_table = (const float*)d_in[4];
    const float* Wp          = (const float*)d_in[5];
    const float* bp          = (const float*)d_in[6];
    const float* conv_w      = (const float*)d_in[7];
    const float* conv_b      = (const float*)d_in[8];
    const float* attn_a      = (const float*)d_in[9];

    float* out    = (float*)d_out;
    float* code   = out;                  // [B*O] = 4096
    float* nodesA = out + 4096;           // [BN*256]  (final nodes output)

    float* ws      = (float*)d_ws;
    float* nodesB  = ws;                      // [BN*256]
    float* wmask   = ws + (size_t)BN * 256;   // [BN]
    float* partial = wmask + BN;              // [128*256]
    unsigned short* whi = (unsigned short*)(partial + 128 * 256);  // [2][196608]
    unsigned short* wlo = whi + 2 * 196608;

    constexpr int LSTRIDE = 196608;           // packed shorts per layer

    pack_w_kernel<<<192, 256, 0, stream>>>(conv_w, whi, wlo);

    emb_parent_kernel<<<BN / BQ, 256, 0, stream>>>(
        node_type, node_tokens, type_table, token_table, Wp, bp, nodesA);

    conv_mfma_kernel<<<BN / CQ, 512, 0, stream>>>(
        nodesA, children, whi, wlo, conv_b, nodesB);

    conv_mfma_kernel<<<BN / CQ, 512, 0, stream>>>(
        nodesB, children, whi + LSTRIDE, wlo + LSTRIDE, conv_b + 256, nodesA);

    score_kernel<<<BN / 4, 256, 0, stream>>>(nodesA, node_type, attn_a, wmask);

    partial_kernel<<<128, 256, 0, stream>>>(nodesA, wmask, partial);

    final_kernel<<<16, 256, 0, stream>>>(partial, code);
}

// Round 4
// 209.898 us; speedup vs baseline: 2.7731x; 2.2985x over previous
//
#include <hip/hip_runtime.h>
#include <math.h>

// Problem constants (from reference)
constexpr int Bsz = 16, Nn = 1024, Cc = 16, Ss = 8;
constexpr int BN = Bsz * Nn;            // 16384 nodes total
constexpr int BQ = 16;                  // nodes per block (emb kernel)
constexpr int CQ = 16;                  // nodes per block (conv kernel)

typedef __attribute__((ext_vector_type(8))) short bf16x8;
typedef __attribute__((ext_vector_type(4))) float f32x4;

__device__ inline unsigned short f2bf_rne(float x) {
    unsigned u = __builtin_bit_cast(unsigned, x);
    unsigned r = (u + 0x7FFFu + ((u >> 16) & 1u)) >> 16;
    return (unsigned short)r;
}
__device__ inline float bf2f(unsigned short h) {
    unsigned u = ((unsigned)h) << 16;
    return __builtin_bit_cast(float, u);
}

// ---------------------------------------------------------------------------
// Kernel 0: pack conv weights into MFMA-fragment-major hi/lo bf16.
// dst[((kb*4+g)*256+col)*8+i] = W[(kb*32+g*8+i)*256+col],  kb<24, g<4
// ---------------------------------------------------------------------------
__global__ __launch_bounds__(256) void pack_w_kernel(
    const float* __restrict__ conv_w,          // [2][768][256]
    unsigned short* __restrict__ whi, unsigned short* __restrict__ wlo)
{
    const int t = blockIdx.x * 256 + threadIdx.x;    // 0..49151
    const int col = t & 255;
    const int gg  = (t >> 8) & 3;
    const int kb  = (t >> 10) % 24;
    const int l   = t / (24 * 4 * 256);
    const float* W = conv_w + (size_t)l * 768 * 256;
    const size_t dst = (size_t)t * 8;
    #pragma unroll
    for (int i = 0; i < 8; ++i) {
        const float x = W[(size_t)(kb * 32 + gg * 8 + i) * 256 + col];
        const unsigned short h = f2bf_rne(x);
        whi[dst + i] = h;
        wlo[dst + i] = f2bf_rne(x - bf2f(h));
    }
}

// ---------------------------------------------------------------------------
// Kernel 1: fused embeddings + parent projection (fp32)
// ---------------------------------------------------------------------------
__global__ __launch_bounds__(256) void emb_parent_kernel(
    const int* __restrict__ node_type, const int* __restrict__ node_tokens,
    const float* __restrict__ type_table, const float* __restrict__ token_table,
    const float* __restrict__ Wp, const float* __restrict__ bp,
    float* __restrict__ out)
{
    __shared__ float emb[BQ][256];
    const int tid = threadIdx.x;
    const int g0 = blockIdx.x * BQ;

    for (int r = 0; r < BQ; ++r) {
        const int g = g0 + r;
        float v;
        if (tid < 128) {
            v = type_table[node_type[g] * 128 + tid];
        } else {
            const int dd = tid - 128;
            float s = 0.f;
            #pragma unroll
            for (int si = 0; si < Ss; ++si)
                s += token_table[node_tokens[g * Ss + si] * 128 + dd];
            v = s;
        }
        emb[r][tid] = v;
    }
    __syncthreads();

    const int o = tid;
    float acc[BQ];
    const float bias = bp[o];
    #pragma unroll
    for (int r = 0; r < BQ; ++r) acc[r] = bias;

    for (int k = 0; k < 256; k += 4) {
        const float w0 = Wp[(k + 0) * 256 + o];
        const float w1 = Wp[(k + 1) * 256 + o];
        const float w2 = Wp[(k + 2) * 256 + o];
        const float w3 = Wp[(k + 3) * 256 + o];
        #pragma unroll
        for (int r = 0; r < BQ; ++r) {
            const float4 mv = *reinterpret_cast<const float4*>(&emb[r][k]);
            float a = acc[r];
            a = fmaf(mv.x, w0, a);
            a = fmaf(mv.y, w1, a);
            a = fmaf(mv.z, w2, a);
            a = fmaf(mv.w, w3, a);
            acc[r] = a;
        }
    }
    for (int r = 0; r < BQ; ++r) out[(size_t)(g0 + r) * 256 + o] = acc[r];
}

// ---------------------------------------------------------------------------
// Kernel 2: tree-conv layer, split-bf16 MFMA, latency-optimized.
// 16 rows/block, 256 threads (4 waves), wave w -> cols [64w, 64w+64).
// B fragments: manual 2-deep register pipeline, int-offset addressing.
// Gather: branch-free (mask folded into eta coefficients).
// ---------------------------------------------------------------------------
__global__ __launch_bounds__(256, 3) void conv_mfma_kernel(
    const float* __restrict__ in_nodes,
    const int* __restrict__ children_index,
    const unsigned short* __restrict__ whi,   // layer offset pre-applied
    const unsigned short* __restrict__ wlo,
    const float* __restrict__ bias,           // [256]
    float* __restrict__ out_nodes)
{
    constexpr int AP = 776;                   // padded k-stride (bf16 elems)
    __shared__ unsigned short Ahi[CQ][AP];
    __shared__ unsigned short Alo[CQ][AP];
    __shared__ int   idxs[CQ][Cc];
    __shared__ float etar[CQ][Cc];
    __shared__ float etal[CQ][Cc];

    const int tid = threadIdx.x;
    const int g0 = blockIdx.x * CQ;
    const int b  = g0 >> 10;
    const float* inb = in_nodes + (size_t)b * Nn * 256;

    // phase 1: children indices + TBCNN coefficients (one (r,c) per thread)
    {
        const int r = tid >> 4, c = tid & 15;
        idxs[r][c] = children_index[(size_t)(g0 + r) * Cc + c];
    }
    __syncthreads();
    {
        const int r = tid >> 4, c = tid & 15;
        int ns = 0;
        #pragma unroll
        for (int j = 0; j < Cc; ++j) ns += (idxs[r][j] > 0) ? 1 : 0;
        const bool cm = idxs[r][c] > 0;
        float er;
        if (ns == 1) {
            er = (c == 0) ? 0.5f : 0.f;       // reference's "singles" quirk
        } else {
            const float denom = (float)((ns - 1 > 1) ? (ns - 1) : 1);
            er = (float)c / denom;
        }
        // fold child-validity mask into the stored coefficients so the
        // gather can load unconditionally (ci==0 row contributes 0)
        etar[r][c] = cm ? er : 0.f;
        etal[r][c] = cm ? (1.f - er) : 0.f;
    }
    __syncthreads();

    // phase 2: gather + mix -> hi/lo bf16 LDS tile [16][768], branch-free
    {
        const int dd = tid;                   // 0..255
        for (int r = 0; r < CQ; ++r) {
            const float m0 = in_nodes[(size_t)(g0 + r) * 256 + dd];
            float m1 = 0.f, m2 = 0.f;
            #pragma unroll
            for (int c = 0; c < Cc; ++c) {
                const int ci = idxs[r][c];
                const float v = inb[(size_t)ci * 256 + dd];
                m1 = fmaf(etar[r][c], v, m1);
                m2 = fmaf(etal[r][c], v, m2);
            }
            const unsigned short h0 = f2bf_rne(m0);
            const unsigned short h1 = f2bf_rne(m1);
            const unsigned short h2 = f2bf_rne(m2);
            Ahi[r][dd]       = h0;  Alo[r][dd]       = f2bf_rne(m0 - bf2f(h0));
            Ahi[r][256 + dd] = h1;  Alo[r][256 + dd] = f2bf_rne(m1 - bf2f(h1));
            Ahi[r][512 + dd] = h2;  Alo[r][512 + dd] = f2bf_rne(m2 - bf2f(h2));
        }
    }
    __syncthreads();

    // phase 3: MFMA GEMM [16 x 768] @ [768 x 256], 2-deep B pipeline
    const int lane = tid & 63;
    const int w    = tid >> 6;
    const int colg = w * 64;
    const int rr   = lane & 15;               // A row / B,D col-within-16
    const int g    = lane >> 4;               // k-subgroup

    // byte strides: frag idx = (kb*4+g)*256 + colg + f*16 + rr, *16 bytes
    const unsigned short* pwh = whi + ((size_t)(g * 256 + colg + rr)) * 8;
    const unsigned short* pwl = wlo + ((size_t)(g * 256 + colg + rr)) * 8;
    // shorts offsets: kb -> kb*8192, f -> f*128

    f32x4 acc[4];
    #pragma unroll
    for (int f = 0; f < 4; ++f) acc[f] = (f32x4){0.f, 0.f, 0.f, 0.f};

    bf16x8 bhA[4], blA[4], bhB[4], blB[4];
    #pragma unroll
    for (int f = 0; f < 4; ++f) {
        bhA[f] = *reinterpret_cast<const bf16x8*>(pwh + f * 128);
        blA[f] = *reinterpret_cast<const bf16x8*>(pwl + f * 128);
    }

    for (int kb = 0; kb < 24; kb += 2) {
        // prefetch kb+1 into B set
        {
            const int o1 = (kb + 1) * 8192;
            #pragma unroll
            for (int f = 0; f < 4; ++f) {
                bhB[f] = *reinterpret_cast<const bf16x8*>(pwh + o1 + f * 128);
                blB[f] = *reinterpret_cast<const bf16x8*>(pwl + o1 + f * 128);
            }
        }
        {
            const int k0 = kb * 32 + g * 8;
            const bf16x8 ah = *reinterpret_cast<const bf16x8*>(&Ahi[rr][k0]);
            const bf16x8 al = *reinterpret_cast<const bf16x8*>(&Alo[rr][k0]);
            #pragma unroll
            for (int f = 0; f < 4; ++f) {
                acc[f] = __builtin_amdgcn_mfma_f32_16x16x32_bf16(ah, bhA[f], acc[f], 0, 0, 0);
                acc[f] = __builtin_amdgcn_mfma_f32_16x16x32_bf16(ah, blA[f], acc[f], 0, 0, 0);
                acc[f] = __builtin_amdgcn_mfma_f32_16x16x32_bf16(al, bhA[f], acc[f], 0, 0, 0);
            }
        }
        // prefetch kb+2 into A set
        if (kb + 2 < 24) {
            const int o2 = (kb + 2) * 8192;
            #pragma unroll
            for (int f = 0; f < 4; ++f) {
                bhA[f] = *reinterpret_cast<const bf16x8*>(pwh + o2 + f * 128);
                blA[f] = *reinterpret_cast<const bf16x8*>(pwl + o2 + f * 128);
            }
        }
        {
            const int k0 = (kb + 1) * 32 + g * 8;
            const bf16x8 ah = *reinterpret_cast<const bf16x8*>(&Ahi[rr][k0]);
            const bf16x8 al = *reinterpret_cast<const bf16x8*>(&Alo[rr][k0]);
            #pragma unroll
            for (int f = 0; f < 4; ++f) {
                acc[f] = __builtin_amdgcn_mfma_f32_16x16x32_bf16(ah, bhB[f], acc[f], 0, 0, 0);
                acc[f] = __builtin_amdgcn_mfma_f32_16x16x32_bf16(ah, blB[f], acc[f], 0, 0, 0);
                acc[f] = __builtin_amdgcn_mfma_f32_16x16x32_bf16(al, bhB[f], acc[f], 0, 0, 0);
            }
        }
    }

    // epilogue: D row = g*4+i, col = colg + f*16 + rr
    #pragma unroll
    for (int f = 0; f < 4; ++f) {
        const int col = colg + f * 16 + rr;
        const float bv = bias[col];
        #pragma unroll
        for (int i = 0; i < 4; ++i) {
            const int row = g * 4 + i;
            out_nodes[(size_t)(g0 + row) * 256 + col] = tanhf(acc[f][i] + bv);
        }
    }
}

// ---------------------------------------------------------------------------
// Kernel 3: attention score -> masked sigmoid weight per node
// ---------------------------------------------------------------------------
__global__ __launch_bounds__(256) void score_kernel(
    const float* __restrict__ nodes, const int* __restrict__ node_type,
    const float* __restrict__ attn_a, float* __restrict__ wmask)
{
    const int tid  = threadIdx.x;
    const int lane = tid & 63, wid = tid >> 6;
    const int g = blockIdx.x * 4 + wid;
    const float* row = nodes + (size_t)g * 256;
    float s = 0.f;
    #pragma unroll
    for (int j = 0; j < 4; ++j)
        s = fmaf(row[lane + 64 * j], attn_a[lane + 64 * j], s);
    #pragma unroll
    for (int off = 32; off > 0; off >>= 1) s += __shfl_down(s, off, 64);
    if (lane == 0) {
        float wm = 0.f;
        if (node_type[g] != 0) wm = 1.f / (1.f + expf(-s));
        wmask[g] = wm;
    }
}

// ---------------------------------------------------------------------------
// Kernel 4/5: masked weighted mean over N (two-stage, deterministic)
// ---------------------------------------------------------------------------
__global__ __launch_bounds__(256) void partial_kernel(
    const float* __restrict__ nodes, const float* __restrict__ wmask,
    float* __restrict__ partial)     // [128][256]
{
    const int blk = blockIdx.x;           // 0..127
    const int b = blk >> 3, chunk = blk & 7;
    const int o = threadIdx.x;
    const int n0 = chunk * 128;
    const float* base = nodes + ((size_t)b * Nn + n0) * 256;
    const float* wm   = wmask + b * Nn + n0;
    float acc = 0.f;
    for (int n = 0; n < 128; ++n) acc = fmaf(base[(size_t)n * 256 + o], wm[n], acc);
    partial[blk * 256 + o] = acc;
}

__global__ __launch_bounds__(256) void final_kernel(
    const float* __restrict__ partial, float* __restrict__ code)
{
    const int i = blockIdx.x * 256 + threadIdx.x;  // 0..4095
    const int b = i >> 8, o = i & 255;
    float acc = 0.f;
    #pragma unroll
    for (int c = 0; c < 8; ++c) acc += partial[(b * 8 + c) * 256 + o];
    code[i] = acc * (1.f / 1024.f);
}

// ---------------------------------------------------------------------------
extern "C" void kernel_launch(void* const* d_in, const int* in_sizes, int n_in,
                              void* d_out, int out_size, void* d_ws, size_t ws_size,
                              hipStream_t stream)
{
    const int*   node_type   = (const int*)d_in[0];
    const int*   node_tokens = (const int*)d_in[1];
    const int*   children    = (const int*)d_in[2];
    const float* type_table  = (const float*)d_in[3];
    const float* token_table = (const float*)d_in[4];
    const float* Wp          = (const float*)d_in[5];
    const float* bp          = (const float*)d_in[6];
    const float* conv_w      = (const float*)d_in[7];
    const float* conv_b      = (const float*)d_in[8];
    const float* attn_a      = (const float*)d_in[9];

    float* out    = (float*)d_out;
    float* code   = out;                  // [B*O] = 4096
    float* nodesA = out + 4096;           // [BN*256]  (final nodes output)

    float* ws      = (float*)d_ws;
    float* nodesB  = ws;                      // [BN*256]
    float* wmask   = ws + (size_t)BN * 256;   // [BN]
    float* partial = wmask + BN;              // [128*256]
    unsigned short* whi = (unsigned short*)(partial + 128 * 256);  // [2][196608]
    unsigned short* wlo = whi + 2 * 196608;

    constexpr int LSTRIDE = 196608;           // packed shorts per layer

    pack_w_kernel<<<192, 256, 0, stream>>>(conv_w, whi, wlo);

    emb_parent_kernel<<<BN / BQ, 256, 0, stream>>>(
        node_type, node_tokens, type_table, token_table, Wp, bp, nodesA);

    conv_mfma_kernel<<<BN / CQ, 256, 0, stream>>>(
        nodesA, children, whi, wlo, conv_b, nodesB);

    conv_mfma_kernel<<<BN / CQ, 256, 0, stream>>>(
        nodesB, children, whi + LSTRIDE, wlo + LSTRIDE, conv_b + 256, nodesA);

    score_kernel<<<BN / 4, 256, 0, stream>>>(nodesA, node_type, attn_a, wmask);

    partial_kernel<<<128, 256, 0, stream>>>(nodesA, wmask, partial);

    final_kernel<<<16, 256, 0, stream>>>(partial, code);
}

// Round 5
// 129.282 us; speedup vs baseline: 4.5022x; 1.6236x over previous
//
#include <hip/hip_runtime.h>
#include <hip/hip_fp16.h>
#include <math.h>

// Problem constants (from reference)
constexpr int Bsz = 16, Nn = 1024, Cc = 16, Ss = 8;
constexpr int BN = Bsz * Nn;            // 16384 nodes total
constexpr int BQ = 16;                  // nodes per block (emb kernel)
constexpr int CQ = 16;                  // nodes per block (conv kernel)

typedef __attribute__((ext_vector_type(8))) short bf16x8;
typedef __attribute__((ext_vector_type(4))) float f32x4;
typedef __attribute__((ext_vector_type(4))) unsigned short u16x4;

__device__ inline unsigned short f2bf_rne(float x) {
    unsigned u = __builtin_bit_cast(unsigned, x);
    unsigned r = (u + 0x7FFFu + ((u >> 16) & 1u)) >> 16;
    return (unsigned short)r;
}

// ---------------------------------------------------------------------------
// Kernel 0: pack conv weights into MFMA-fragment-major bf16.
// dst[((kb*4+g)*256+col)*8+i] = W[(kb*32+g*8+i)*256+col],  kb<24, g<4
// ---------------------------------------------------------------------------
__global__ __launch_bounds__(256) void pack_w_kernel(
    const float* __restrict__ conv_w,          // [2][768][256]
    unsigned short* __restrict__ whi)
{
    const int t = blockIdx.x * 256 + threadIdx.x;    // 0..49151
    const int col = t & 255;
    const int gg  = (t >> 8) & 3;
    const int kb  = (t >> 10) % 24;
    const int l   = t / (24 * 4 * 256);
    const float* W = conv_w + (size_t)l * 768 * 256;
    const size_t dst = (size_t)t * 8;
    #pragma unroll
    for (int i = 0; i < 8; ++i) {
        const float x = W[(size_t)(kb * 32 + gg * 8 + i) * 256 + col];
        whi[dst + i] = f2bf_rne(x);
    }
}

// ---------------------------------------------------------------------------
// Kernel 1: fused embeddings + parent projection (fp32)
// ---------------------------------------------------------------------------
__global__ __launch_bounds__(256) void emb_parent_kernel(
    const int* __restrict__ node_type, const int* __restrict__ node_tokens,
    const float* __restrict__ type_table, const float* __restrict__ token_table,
    const float* __restrict__ Wp, const float* __restrict__ bp,
    float* __restrict__ out)
{
    __shared__ float emb[BQ][256];
    const int tid = threadIdx.x;
    const int g0 = blockIdx.x * BQ;

    for (int r = 0; r < BQ; ++r) {
        const int g = g0 + r;
        float v;
        if (tid < 128) {
            v = type_table[node_type[g] * 128 + tid];
        } else {
            const int dd = tid - 128;
            float s = 0.f;
            #pragma unroll
            for (int si = 0; si < Ss; ++si)
                s += token_table[node_tokens[g * Ss + si] * 128 + dd];
            v = s;
        }
        emb[r][tid] = v;
    }
    __syncthreads();

    const int o = tid;
    float acc[BQ];
    const float bias = bp[o];
    #pragma unroll
    for (int r = 0; r < BQ; ++r) acc[r] = bias;

    for (int k = 0; k < 256; k += 4) {
        const float w0 = Wp[(k + 0) * 256 + o];
        const float w1 = Wp[(k + 1) * 256 + o];
        const float w2 = Wp[(k + 2) * 256 + o];
        const float w3 = Wp[(k + 3) * 256 + o];
        #pragma unroll
        for (int r = 0; r < BQ; ++r) {
            const float4 mv = *reinterpret_cast<const float4*>(&emb[r][k]);
            float a = acc[r];
            a = fmaf(mv.x, w0, a);
            a = fmaf(mv.y, w1, a);
            a = fmaf(mv.z, w2, a);
            a = fmaf(mv.w, w3, a);
            acc[r] = a;
        }
    }
    for (int r = 0; r < BQ; ++r) out[(size_t)(g0 + r) * 256 + o] = acc[r];
}

// ---------------------------------------------------------------------------
// Kernel 2: tree-conv layer, pure-bf16 MFMA, occupancy-optimized.
// 16 rows/block, 256 threads (4 waves), wave w -> cols [64w, 64w+64).
// float4-vectorized gather; XCD-swizzled blocks (batch -> one XCD's L2).
// ---------------------------------------------------------------------------
__global__ __launch_bounds__(256, 6) void conv_mfma_kernel(
    const float* __restrict__ in_nodes,
    const int* __restrict__ children_index,
    const unsigned short* __restrict__ whi,   // layer offset pre-applied
    const float* __restrict__ bias,           // [256]
    float* __restrict__ out_nodes)
{
    constexpr int AP = 776;                   // padded k-stride (bf16 elems)
    __shared__ unsigned short Ahi[CQ][AP];    // 24.8 KB
    __shared__ unsigned short idx_s[CQ][Cc];  // 0.5 KB
    __shared__ __half eta_s[2][CQ][Cc];       // 1 KB   [0]=eta_r [1]=eta_l

    const int tid = threadIdx.x;

    // XCD swizzle: 64 blocks per batch; batch b -> XCD b%8 (heuristic).
    // launch idx P = (b%8) + 8*j + 512*(b/8), j<64 -> decode:
    const int P = blockIdx.x;
    const int xx = P & 7;
    const int rst = P >> 3;
    const int j = rst & 63;
    const int yy = rst >> 6;
    const int batch = xx + 8 * yy;
    const int g0 = batch * Nn + j * CQ;
    const float* inb = in_nodes + (size_t)batch * Nn * 256;

    // phase 1: children indices + TBCNN coefficients
    {
        const int r = tid >> 4, c = tid & 15;
        idx_s[r][c] = (unsigned short)children_index[(size_t)(g0 + r) * Cc + c];
    }
    __syncthreads();
    {
        const int r = tid >> 4, c = tid & 15;
        int ns = 0;
        #pragma unroll
        for (int q = 0; q < Cc; ++q) ns += (idx_s[r][q] > 0) ? 1 : 0;
        const bool cm = idx_s[r][c] > 0;
        float er;
        if (ns == 1) {
            er = (c == 0) ? 0.5f : 0.f;       // reference's "singles" quirk
        } else {
            const float denom = (float)((ns - 1 > 1) ? (ns - 1) : 1);
            er = (float)c / denom;
        }
        // fold child-validity mask in (ci==0 row contributes 0)
        eta_s[0][r][c] = __float2half(cm ? er : 0.f);
        eta_s[1][r][c] = __float2half(cm ? (1.f - er) : 0.f);
    }
    __syncthreads();

    // phase 2: float4 gather + mix -> bf16 LDS tile [16][768]
    {
        const int q = tid & 63;               // float4 chunk within row
        const int rgrp = tid >> 6;            // wave id
        #pragma unroll
        for (int rr4 = 0; rr4 < 4; ++rr4) {
            const int r = rgrp + rr4 * 4;     // all lanes of wave share r
            const float4 m0 = *reinterpret_cast<const float4*>(
                in_nodes + (size_t)(g0 + r) * 256 + q * 4);
            float4 m1 = {0.f, 0.f, 0.f, 0.f};
            float4 m2 = {0.f, 0.f, 0.f, 0.f};
            #pragma unroll
            for (int c = 0; c < Cc; ++c) {
                const int ci = idx_s[r][c];
                const float4 v = *reinterpret_cast<const float4*>(
                    inb + (size_t)ci * 256 + q * 4);
                const float er = __half2float(eta_s[0][r][c]);
                const float el = __half2float(eta_s[1][r][c]);
                m1.x = fmaf(er, v.x, m1.x); m1.y = fmaf(er, v.y, m1.y);
                m1.z = fmaf(er, v.z, m1.z); m1.w = fmaf(er, v.w, m1.w);
                m2.x = fmaf(el, v.x, m2.x); m2.y = fmaf(el, v.y, m2.y);
                m2.z = fmaf(el, v.z, m2.z); m2.w = fmaf(el, v.w, m2.w);
            }
            u16x4 s0, s1, s2;
            s0.x = f2bf_rne(m0.x); s0.y = f2bf_rne(m0.y);
            s0.z = f2bf_rne(m0.z); s0.w = f2bf_rne(m0.w);
            s1.x = f2bf_rne(m1.x); s1.y = f2bf_rne(m1.y);
            s1.z = f2bf_rne(m1.z); s1.w = f2bf_rne(m1.w);
            s2.x = f2bf_rne(m2.x); s2.y = f2bf_rne(m2.y);
            s2.z = f2bf_rne(m2.z); s2.w = f2bf_rne(m2.w);
            *reinterpret_cast<u16x4*>(&Ahi[r][q * 4])       = s0;
            *reinterpret_cast<u16x4*>(&Ahi[r][256 + q * 4]) = s1;
            *reinterpret_cast<u16x4*>(&Ahi[r][512 + q * 4]) = s2;
        }
    }
    __syncthreads();

    // phase 3: MFMA GEMM [16 x 768] @ [768 x 256], 2-deep B pipeline
    const int lane = tid & 63;
    const int w    = tid >> 6;
    const int colg = w * 64;
    const int rr   = lane & 15;               // A row / B,D col-within-16
    const int g    = lane >> 4;               // k-subgroup

    const unsigned short* pwh = whi + ((size_t)(g * 256 + colg + rr)) * 8;
    // shorts offsets: kb -> kb*8192, f -> f*128

    f32x4 acc[4];
    #pragma unroll
    for (int f = 0; f < 4; ++f) acc[f] = (f32x4){0.f, 0.f, 0.f, 0.f};

    bf16x8 bA[4], bB[4];
    #pragma unroll
    for (int f = 0; f < 4; ++f)
        bA[f] = *reinterpret_cast<const bf16x8*>(pwh + f * 128);

    for (int kb = 0; kb < 24; kb += 2) {
        {
            const int o1 = (kb + 1) * 8192;
            #pragma unroll
            for (int f = 0; f < 4; ++f)
                bB[f] = *reinterpret_cast<const bf16x8*>(pwh + o1 + f * 128);
        }
        {
            const int k0 = kb * 32 + g * 8;
            const bf16x8 ah = *reinterpret_cast<const bf16x8*>(&Ahi[rr][k0]);
            #pragma unroll
            for (int f = 0; f < 4; ++f)
                acc[f] = __builtin_amdgcn_mfma_f32_16x16x32_bf16(ah, bA[f], acc[f], 0, 0, 0);
        }
        if (kb + 2 < 24) {
            const int o2 = (kb + 2) * 8192;
            #pragma unroll
            for (int f = 0; f < 4; ++f)
                bA[f] = *reinterpret_cast<const bf16x8*>(pwh + o2 + f * 128);
        }
        {
            const int k0 = (kb + 1) * 32 + g * 8;
            const bf16x8 ah = *reinterpret_cast<const bf16x8*>(&Ahi[rr][k0]);
            #pragma unroll
            for (int f = 0; f < 4; ++f)
                acc[f] = __builtin_amdgcn_mfma_f32_16x16x32_bf16(ah, bB[f], acc[f], 0, 0, 0);
        }
    }

    // epilogue: D row = g*4+i, col = colg + f*16 + rr
    #pragma unroll
    for (int f = 0; f < 4; ++f) {
        const int col = colg + f * 16 + rr;
        const float bv = bias[col];
        #pragma unroll
        for (int i = 0; i < 4; ++i) {
            const int row = g * 4 + i;
            out_nodes[(size_t)(g0 + row) * 256 + col] = tanhf(acc[f][i] + bv);
        }
    }
}

// ---------------------------------------------------------------------------
// Kernel 3: attention score -> masked sigmoid weight per node
// ---------------------------------------------------------------------------
__global__ __launch_bounds__(256) void score_kernel(
    const float* __restrict__ nodes, const int* __restrict__ node_type,
    const float* __restrict__ attn_a, float* __restrict__ wmask)
{
    const int tid  = threadIdx.x;
    const int lane = tid & 63, wid = tid >> 6;
    const int g = blockIdx.x * 4 + wid;
    const float* row = nodes + (size_t)g * 256;
    float s = 0.f;
    #pragma unroll
    for (int j = 0; j < 4; ++j)
        s = fmaf(row[lane + 64 * j], attn_a[lane + 64 * j], s);
    #pragma unroll
    for (int off = 32; off > 0; off >>= 1) s += __shfl_down(s, off, 64);
    if (lane == 0) {
        float wm = 0.f;
        if (node_type[g] != 0) wm = 1.f / (1.f + expf(-s));
        wmask[g] = wm;
    }
}

// ---------------------------------------------------------------------------
// Kernel 4/5: masked weighted mean over N (two-stage, deterministic)
// ---------------------------------------------------------------------------
__global__ __launch_bounds__(256) void partial_kernel(
    const float* __restrict__ nodes, const float* __restrict__ wmask,
    float* __restrict__ partial)     // [512][256]
{
    const int blk = blockIdx.x;           // 0..511
    const int b = blk >> 5, chunk = blk & 31;
    const int o = threadIdx.x;
    const int n0 = chunk * 32;
    const float* base = nodes + ((size_t)b * Nn + n0) * 256;
    const float* wm   = wmask + b * Nn + n0;
    float acc = 0.f;
    #pragma unroll 8
    for (int n = 0; n < 32; ++n) acc = fmaf(base[(size_t)n * 256 + o], wm[n], acc);
    partial[blk * 256 + o] = acc;
}

__global__ __launch_bounds__(256) void final_kernel(
    const float* __restrict__ partial, float* __restrict__ code)
{
    const int i = blockIdx.x * 256 + threadIdx.x;  // 0..4095
    const int b = i >> 8, o = i & 255;
    float acc = 0.f;
    #pragma unroll
    for (int c = 0; c < 32; ++c) acc += partial[(b * 32 + c) * 256 + o];
    code[i] = acc * (1.f / 1024.f);
}

// ---------------------------------------------------------------------------
extern "C" void kernel_launch(void* const* d_in, const int* in_sizes, int n_in,
                              void* d_out, int out_size, void* d_ws, size_t ws_size,
                              hipStream_t stream)
{
    const int*   node_type   = (const int*)d_in[0];
    const int*   node_tokens = (const int*)d_in[1];
    const int*   children    = (const int*)d_in[2];
    const float* type_table  = (const float*)d_in[3];
    const float* token_table = (const float*)d_in[4];
    const float* Wp          = (const float*)d_in[5];
    const float* bp          = (const float*)d_in[6];
    const float* conv_w      = (const float*)d_in[7];
    const float* conv_b      = (const float*)d_in[8];
    const float* attn_a      = (const float*)d_in[9];

    float* out    = (float*)d_out;
    float* code   = out;                  // [B*O] = 4096
    float* nodesA = out + 4096;           // [BN*256]  (final nodes output)

    float* ws      = (float*)d_ws;
    float* nodesB  = ws;                      // [BN*256]
    float* wmask   = ws + (size_t)BN * 256;   // [BN]
    float* partial = wmask + BN;              // [512*256]
    unsigned short* whi = (unsigned short*)(partial + 512 * 256);  // [2][196608]

    constexpr int LSTRIDE = 196608;           // packed shorts per layer

    pack_w_kernel<<<192, 256, 0, stream>>>(conv_w, whi);

    emb_parent_kernel<<<BN / BQ, 256, 0, stream>>>(
        node_type, node_tokens, type_table, token_table, Wp, bp, nodesA);

    conv_mfma_kernel<<<BN / CQ, 256, 0, stream>>>(
        nodesA, children, whi, conv_b, nodesB);

    conv_mfma_kernel<<<BN / CQ, 256, 0, stream>>>(
        nodesB, children, whi + LSTRIDE, conv_b + 256, nodesA);

    score_kernel<<<BN / 4, 256, 0, stream>>>(nodesA, node_type, attn_a, wmask);

    partial_kernel<<<512, 256, 0, stream>>>(nodesA, wmask, partial);

    final_kernel<<<16, 256, 0, stream>>>(partial, code);
}

// Round 6
// 97.090 us; speedup vs baseline: 5.9950x; 1.3316x over previous
//
#include <hip/hip_runtime.h>
#include <hip/hip_fp16.h>
#include <math.h>

// Problem constants (from reference)
constexpr int Bsz = 16, Nn = 1024, Cc = 16, Ss = 8;
constexpr int BN = Bsz * Nn;            // 16384 nodes total
constexpr int CQ = 16;                  // nodes per block (conv + emb kernels)

typedef __attribute__((ext_vector_type(8))) short bf16x8;
typedef __attribute__((ext_vector_type(4))) float f32x4;
typedef __attribute__((ext_vector_type(4))) unsigned short u16x4;

__device__ inline unsigned short f2bf_rne(float x) {
    unsigned u = __builtin_bit_cast(unsigned, x);
    unsigned r = (u + 0x7FFFu + ((u >> 16) & 1u)) >> 16;
    return (unsigned short)r;
}

// ---------------------------------------------------------------------------
// Kernel 0a: pack conv weights into MFMA-fragment-major bf16.
// dst[((kb*4+g)*256+col)*8+i] = W[(kb*32+g*8+i)*256+col],  kb<24, g<4
// ---------------------------------------------------------------------------
__global__ __launch_bounds__(256) void pack_w_kernel(
    const float* __restrict__ conv_w,          // [2][768][256]
    unsigned short* __restrict__ whi)
{
    const int t = blockIdx.x * 256 + threadIdx.x;    // 0..49151
    const int col = t & 255;
    const int gg  = (t >> 8) & 3;
    const int kb  = (t >> 10) % 24;
    const int l   = t / (24 * 4 * 256);
    const float* W = conv_w + (size_t)l * 768 * 256;
    const size_t dst = (size_t)t * 8;
    #pragma unroll
    for (int i = 0; i < 8; ++i) {
        const float x = W[(size_t)(kb * 32 + gg * 8 + i) * 256 + col];
        whi[dst + i] = f2bf_rne(x);
    }
}

// ---------------------------------------------------------------------------
// Kernel 0b: pack W_parent [256][256] the same way (kb<8).
// ---------------------------------------------------------------------------
__global__ __launch_bounds__(256) void pack_wp_kernel(
    const float* __restrict__ Wp,              // [256][256]
    unsigned short* __restrict__ wpq)
{
    const int t = blockIdx.x * 256 + threadIdx.x;    // 0..8191
    const int col = t & 255;
    const int gg  = (t >> 8) & 3;
    const int kb  = t >> 10;                          // 0..7
    const size_t dst = (size_t)t * 8;
    #pragma unroll
    for (int i = 0; i < 8; ++i) {
        const float x = Wp[(size_t)(kb * 32 + gg * 8 + i) * 256 + col];
        wpq[dst + i] = f2bf_rne(x);
    }
}

// ---------------------------------------------------------------------------
// Kernel 1: fused embeddings + parent projection via MFMA.
// 16 rows/block, 256 threads (4 waves). Phase 1: wave w builds rows
// {4w..4w+3} of the bf16 emb tile (lanes 0-31: type float4; lanes 32-63:
// 8-way token float4 sum). Phase 2: [16x256]@[256x256] MFMA GEMM.
// ---------------------------------------------------------------------------
__global__ __launch_bounds__(256, 4) void emb_mfma_kernel(
    const int* __restrict__ node_type, const int* __restrict__ node_tokens,
    const float* __restrict__ type_table, const float* __restrict__ token_table,
    const unsigned short* __restrict__ wpq,   // packed W_parent
    const float* __restrict__ bp,
    float* __restrict__ out)
{
    constexpr int AP = 264;                   // padded stride (bf16 elems)
    __shared__ unsigned short A[CQ][AP];      // 8.25 KB

    const int tid  = threadIdx.x;
    const int lane = tid & 63;
    const int w    = tid >> 6;
    const int g0   = blockIdx.x * CQ;

    // phase 1: build bf16 emb tile
    #pragma unroll
    for (int it = 0; it < 4; ++it) {
        const int r = w * 4 + it;
        const int gnode = g0 + r;
        if (lane < 32) {
            const int tt = node_type[gnode];
            const float4 v = *reinterpret_cast<const float4*>(
                type_table + (size_t)tt * 128 + lane * 4);
            u16x4 s;
            s.x = f2bf_rne(v.x); s.y = f2bf_rne(v.y);
            s.z = f2bf_rne(v.z); s.w = f2bf_rne(v.w);
            *reinterpret_cast<u16x4*>(&A[r][lane * 4]) = s;
        } else {
            const int q = lane - 32;
            float4 acc = {0.f, 0.f, 0.f, 0.f};
            #pragma unroll
            for (int si = 0; si < Ss; ++si) {
                const int tok = node_tokens[gnode * Ss + si];
                const float4 v = *reinterpret_cast<const float4*>(
                    token_table + (size_t)tok * 128 + q * 4);
                acc.x += v.x; acc.y += v.y; acc.z += v.z; acc.w += v.w;
            }
            u16x4 s;
            s.x = f2bf_rne(acc.x); s.y = f2bf_rne(acc.y);
            s.z = f2bf_rne(acc.z); s.w = f2bf_rne(acc.w);
            *reinterpret_cast<u16x4*>(&A[r][128 + q * 4]) = s;
        }
    }
    __syncthreads();

    // phase 2: MFMA GEMM [16 x 256] @ [256 x 256], 2-deep B pipeline
    const int colg = w * 64;
    const int rr   = lane & 15;
    const int g    = lane >> 4;

    const unsigned short* pwh = wpq + ((size_t)(g * 256 + colg + rr)) * 8;

    f32x4 acc[4];
    #pragma unroll
    for (int f = 0; f < 4; ++f) acc[f] = (f32x4){0.f, 0.f, 0.f, 0.f};

    bf16x8 bA[4], bB[4];
    #pragma unroll
    for (int f = 0; f < 4; ++f)
        bA[f] = *reinterpret_cast<const bf16x8*>(pwh + f * 128);

    for (int kb = 0; kb < 8; kb += 2) {
        {
            const int o1 = (kb + 1) * 8192;
            #pragma unroll
            for (int f = 0; f < 4; ++f)
                bB[f] = *reinterpret_cast<const bf16x8*>(pwh + o1 + f * 128);
        }
        {
            const int k0 = kb * 32 + g * 8;
            const bf16x8 ah = *reinterpret_cast<const bf16x8*>(&A[rr][k0]);
            #pragma unroll
            for (int f = 0; f < 4; ++f)
                acc[f] = __builtin_amdgcn_mfma_f32_16x16x32_bf16(ah, bA[f], acc[f], 0, 0, 0);
        }
        if (kb + 2 < 8) {
            const int o2 = (kb + 2) * 8192;
            #pragma unroll
            for (int f = 0; f < 4; ++f)
                bA[f] = *reinterpret_cast<const bf16x8*>(pwh + o2 + f * 128);
        }
        {
            const int k0 = (kb + 1) * 32 + g * 8;
            const bf16x8 ah = *reinterpret_cast<const bf16x8*>(&A[rr][k0]);
            #pragma unroll
            for (int f = 0; f < 4; ++f)
                acc[f] = __builtin_amdgcn_mfma_f32_16x16x32_bf16(ah, bB[f], acc[f], 0, 0, 0);
        }
    }

    // epilogue: D row = g*4+i, col = colg + f*16 + rr
    #pragma unroll
    for (int f = 0; f < 4; ++f) {
        const int col = colg + f * 16 + rr;
        const float bv = bp[col];
        #pragma unroll
        for (int i = 0; i < 4; ++i) {
            const int row = g * 4 + i;
            out[(size_t)(g0 + row) * 256 + col] = acc[f][i] + bv;
        }
    }
}

// ---------------------------------------------------------------------------
// Kernel 2: tree-conv layer, pure-bf16 MFMA (unchanged from round 5).
// ---------------------------------------------------------------------------
__global__ __launch_bounds__(256, 6) void conv_mfma_kernel(
    const float* __restrict__ in_nodes,
    const int* __restrict__ children_index,
    const unsigned short* __restrict__ whi,   // layer offset pre-applied
    const float* __restrict__ bias,           // [256]
    float* __restrict__ out_nodes)
{
    constexpr int AP = 776;                   // padded k-stride (bf16 elems)
    __shared__ unsigned short Ahi[CQ][AP];    // 24.8 KB
    __shared__ unsigned short idx_s[CQ][Cc];  // 0.5 KB
    __shared__ __half eta_s[2][CQ][Cc];       // 1 KB   [0]=eta_r [1]=eta_l

    const int tid = threadIdx.x;

    // XCD swizzle: 64 blocks per batch; batch b -> XCD b%8 (heuristic).
    const int P = blockIdx.x;
    const int xx = P & 7;
    const int rst = P >> 3;
    const int j = rst & 63;
    const int yy = rst >> 6;
    const int batch = xx + 8 * yy;
    const int g0 = batch * Nn + j * CQ;
    const float* inb = in_nodes + (size_t)batch * Nn * 256;

    // phase 1: children indices + TBCNN coefficients
    {
        const int r = tid >> 4, c = tid & 15;
        idx_s[r][c] = (unsigned short)children_index[(size_t)(g0 + r) * Cc + c];
    }
    __syncthreads();
    {
        const int r = tid >> 4, c = tid & 15;
        int ns = 0;
        #pragma unroll
        for (int q = 0; q < Cc; ++q) ns += (idx_s[r][q] > 0) ? 1 : 0;
        const bool cm = idx_s[r][c] > 0;
        float er;
        if (ns == 1) {
            er = (c == 0) ? 0.5f : 0.f;       // reference's "singles" quirk
        } else {
            const float denom = (float)((ns - 1 > 1) ? (ns - 1) : 1);
            er = (float)c / denom;
        }
        // fold child-validity mask in (ci==0 row contributes 0)
        eta_s[0][r][c] = __float2half(cm ? er : 0.f);
        eta_s[1][r][c] = __float2half(cm ? (1.f - er) : 0.f);
    }
    __syncthreads();

    // phase 2: float4 gather + mix -> bf16 LDS tile [16][768]
    {
        const int q = tid & 63;               // float4 chunk within row
        const int rgrp = tid >> 6;            // wave id
        #pragma unroll
        for (int rr4 = 0; rr4 < 4; ++rr4) {
            const int r = rgrp + rr4 * 4;     // all lanes of wave share r
            const float4 m0 = *reinterpret_cast<const float4*>(
                in_nodes + (size_t)(g0 + r) * 256 + q * 4);
            float4 m1 = {0.f, 0.f, 0.f, 0.f};
            float4 m2 = {0.f, 0.f, 0.f, 0.f};
            #pragma unroll
            for (int c = 0; c < Cc; ++c) {
                const int ci = idx_s[r][c];
                const float4 v = *reinterpret_cast<const float4*>(
                    inb + (size_t)ci * 256 + q * 4);
                const float er = __half2float(eta_s[0][r][c]);
                const float el = __half2float(eta_s[1][r][c]);
                m1.x = fmaf(er, v.x, m1.x); m1.y = fmaf(er, v.y, m1.y);
                m1.z = fmaf(er, v.z, m1.z); m1.w = fmaf(er, v.w, m1.w);
                m2.x = fmaf(el, v.x, m2.x); m2.y = fmaf(el, v.y, m2.y);
                m2.z = fmaf(el, v.z, m2.z); m2.w = fmaf(el, v.w, m2.w);
            }
            u16x4 s0, s1, s2;
            s0.x = f2bf_rne(m0.x); s0.y = f2bf_rne(m0.y);
            s0.z = f2bf_rne(m0.z); s0.w = f2bf_rne(m0.w);
            s1.x = f2bf_rne(m1.x); s1.y = f2bf_rne(m1.y);
            s1.z = f2bf_rne(m1.z); s1.w = f2bf_rne(m1.w);
            s2.x = f2bf_rne(m2.x); s2.y = f2bf_rne(m2.y);
            s2.z = f2bf_rne(m2.z); s2.w = f2bf_rne(m2.w);
            *reinterpret_cast<u16x4*>(&Ahi[r][q * 4])       = s0;
            *reinterpret_cast<u16x4*>(&Ahi[r][256 + q * 4]) = s1;
            *reinterpret_cast<u16x4*>(&Ahi[r][512 + q * 4]) = s2;
        }
    }
    __syncthreads();

    // phase 3: MFMA GEMM [16 x 768] @ [768 x 256], 2-deep B pipeline
    const int lane = tid & 63;
    const int w    = tid >> 6;
    const int colg = w * 64;
    const int rr   = lane & 15;               // A row / B,D col-within-16
    const int g    = lane >> 4;               // k-subgroup

    const unsigned short* pwh = whi + ((size_t)(g * 256 + colg + rr)) * 8;

    f32x4 acc[4];
    #pragma unroll
    for (int f = 0; f < 4; ++f) acc[f] = (f32x4){0.f, 0.f, 0.f, 0.f};

    bf16x8 bA[4], bB[4];
    #pragma unroll
    for (int f = 0; f < 4; ++f)
        bA[f] = *reinterpret_cast<const bf16x8*>(pwh + f * 128);

    for (int kb = 0; kb < 24; kb += 2) {
        {
            const int o1 = (kb + 1) * 8192;
            #pragma unroll
            for (int f = 0; f < 4; ++f)
                bB[f] = *reinterpret_cast<const bf16x8*>(pwh + o1 + f * 128);
        }
        {
            const int k0 = kb * 32 + g * 8;
            const bf16x8 ah = *reinterpret_cast<const bf16x8*>(&Ahi[rr][k0]);
            #pragma unroll
            for (int f = 0; f < 4; ++f)
                acc[f] = __builtin_amdgcn_mfma_f32_16x16x32_bf16(ah, bA[f], acc[f], 0, 0, 0);
        }
        if (kb + 2 < 24) {
            const int o2 = (kb + 2) * 8192;
            #pragma unroll
            for (int f = 0; f < 4; ++f)
                bA[f] = *reinterpret_cast<const bf16x8*>(pwh + o2 + f * 128);
        }
        {
            const int k0 = (kb + 1) * 32 + g * 8;
            const bf16x8 ah = *reinterpret_cast<const bf16x8*>(&Ahi[rr][k0]);
            #pragma unroll
            for (int f = 0; f < 4; ++f)
                acc[f] = __builtin_amdgcn_mfma_f32_16x16x32_bf16(ah, bB[f], acc[f], 0, 0, 0);
        }
    }

    // epilogue: D row = g*4+i, col = colg + f*16 + rr
    #pragma unroll
    for (int f = 0; f < 4; ++f) {
        const int col = colg + f * 16 + rr;
        const float bv = bias[col];
        #pragma unroll
        for (int i = 0; i < 4; ++i) {
            const int row = g * 4 + i;
            out_nodes[(size_t)(g0 + row) * 256 + col] = tanhf(acc[f][i] + bv);
        }
    }
}

// ---------------------------------------------------------------------------
// Kernel 3: attention score -> masked sigmoid weight per node
// ---------------------------------------------------------------------------
__global__ __launch_bounds__(256) void score_kernel(
    const float* __restrict__ nodes, const int* __restrict__ node_type,
    const float* __restrict__ attn_a, float* __restrict__ wmask)
{
    const int tid  = threadIdx.x;
    const int lane = tid & 63, wid = tid >> 6;
    const int g = blockIdx.x * 4 + wid;
    const float* row = nodes + (size_t)g * 256;
    float s = 0.f;
    #pragma unroll
    for (int j = 0; j < 4; ++j)
        s = fmaf(row[lane + 64 * j], attn_a[lane + 64 * j], s);
    #pragma unroll
    for (int off = 32; off > 0; off >>= 1) s += __shfl_down(s, off, 64);
    if (lane == 0) {
        float wm = 0.f;
        if (node_type[g] != 0) wm = 1.f / (1.f + expf(-s));
        wmask[g] = wm;
    }
}

// ---------------------------------------------------------------------------
// Kernel 4/5: masked weighted mean over N (two-stage, deterministic)
// ---------------------------------------------------------------------------
__global__ __launch_bounds__(256) void partial_kernel(
    const float* __restrict__ nodes, const float* __restrict__ wmask,
    float* __restrict__ partial)     // [512][256]
{
    const int blk = blockIdx.x;           // 0..511
    const int b = blk >> 5, chunk = blk & 31;
    const int o = threadIdx.x;
    const int n0 = chunk * 32;
    const float* base = nodes + ((size_t)b * Nn + n0) * 256;
    const float* wm   = wmask + b * Nn + n0;
    float acc = 0.f;
    #pragma unroll 8
    for (int n = 0; n < 32; ++n) acc = fmaf(base[(size_t)n * 256 + o], wm[n], acc);
    partial[blk * 256 + o] = acc;
}

__global__ __launch_bounds__(256) void final_kernel(
    const float* __restrict__ partial, float* __restrict__ code)
{
    const int i = blockIdx.x * 256 + threadIdx.x;  // 0..4095
    const int b = i >> 8, o = i & 255;
    float acc = 0.f;
    #pragma unroll
    for (int c = 0; c < 32; ++c) acc += partial[(b * 32 + c) * 256 + o];
    code[i] = acc * (1.f / 1024.f);
}

// ---------------------------------------------------------------------------
extern "C" void kernel_launch(void* const* d_in, const int* in_sizes, int n_in,
                              void* d_out, int out_size, void* d_ws, size_t ws_size,
                              hipStream_t stream)
{
    const int*   node_type   = (const int*)d_in[0];
    const int*   node_tokens = (const int*)d_in[1];
    const int*   children    = (const int*)d_in[2];
    const float* type_table  = (const float*)d_in[3];
    const float* token_table = (const float*)d_in[4];
    const float* Wp          = (const float*)d_in[5];
    const float* bp          = (const float*)d_in[6];
    const float* conv_w      = (const float*)d_in[7];
    const float* conv_b      = (const float*)d_in[8];
    const float* attn_a      = (const float*)d_in[9];

    float* out    = (float*)d_out;
    float* code   = out;                  // [B*O] = 4096
    float* nodesA = out + 4096;           // [BN*256]  (final nodes output)

    float* ws      = (float*)d_ws;
    float* nodesB  = ws;                      // [BN*256]
    float* wmask   = ws + (size_t)BN * 256;   // [BN]
    float* partial = wmask + BN;              // [512*256]
    unsigned short* whi = (unsigned short*)(partial + 512 * 256);  // [2][196608]
    unsigned short* wpq = whi + 2 * 196608;   // [65536]

    constexpr int LSTRIDE = 196608;           // packed shorts per layer

    pack_w_kernel<<<192, 256, 0, stream>>>(conv_w, whi);
    pack_wp_kernel<<<32, 256, 0, stream>>>(Wp, wpq);

    emb_mfma_kernel<<<BN / CQ, 256, 0, stream>>>(
        node_type, node_tokens, type_table, token_table, wpq, bp, nodesA);

    conv_mfma_kernel<<<BN / CQ, 256, 0, stream>>>(
        nodesA, children, whi, conv_b, nodesB);

    conv_mfma_kernel<<<BN / CQ, 256, 0, stream>>>(
        nodesB, children, whi + LSTRIDE, conv_b + 256, nodesA);

    score_kernel<<<BN / 4, 256, 0, stream>>>(nodesA, node_type, attn_a, wmask);

    partial_kernel<<<512, 256, 0, stream>>>(nodesA, wmask, partial);

    final_kernel<<<16, 256, 0, stream>>>(partial, code);
}

// Round 7
// 93.886 us; speedup vs baseline: 6.1996x; 1.0341x over previous
//
#include <hip/hip_runtime.h>
#include <hip/hip_fp16.h>
#include <math.h>

// Problem constants (from reference)
constexpr int Bsz = 16, Nn = 1024, Cc = 16, Ss = 8;
constexpr int BN = Bsz * Nn;            // 16384 nodes total
constexpr int CQ = 32;                  // nodes per block (emb + conv kernels)

typedef __attribute__((ext_vector_type(8))) short bf16x8;
typedef __attribute__((ext_vector_type(4))) float f32x4;
typedef __attribute__((ext_vector_type(4))) unsigned short u16x4;

__device__ inline unsigned short f2bf_rne(float x) {
    unsigned u = __builtin_bit_cast(unsigned, x);
    unsigned r = (u + 0x7FFFu + ((u >> 16) & 1u)) >> 16;
    return (unsigned short)r;
}

// ---------------------------------------------------------------------------
// Kernel 0: pack conv weights (blocks 0..191) and W_parent (192..223) into
// MFMA-fragment-major bf16: dst[((kb*4+g)*256+col)*8+i] = W[(kb*32+g*8+i)*256+col]
// ---------------------------------------------------------------------------
__global__ __launch_bounds__(256) void pack_all_kernel(
    const float* __restrict__ conv_w,          // [2][768][256]
    const float* __restrict__ Wp,              // [256][256]
    unsigned short* __restrict__ whi, unsigned short* __restrict__ wpq)
{
    if (blockIdx.x < 192) {
        const int t = blockIdx.x * 256 + threadIdx.x;    // 0..49151
        const int col = t & 255;
        const int gg  = (t >> 8) & 3;
        const int kb  = (t >> 10) % 24;
        const int l   = t / (24 * 4 * 256);
        const float* W = conv_w + (size_t)l * 768 * 256;
        const size_t dst = (size_t)t * 8;
        #pragma unroll
        for (int i = 0; i < 8; ++i)
            whi[dst + i] = f2bf_rne(W[(size_t)(kb * 32 + gg * 8 + i) * 256 + col]);
    } else {
        const int t = (blockIdx.x - 192) * 256 + threadIdx.x;  // 0..8191
        const int col = t & 255;
        const int gg  = (t >> 8) & 3;
        const int kb  = t >> 10;                          // 0..7
        const size_t dst = (size_t)t * 8;
        #pragma unroll
        for (int i = 0; i < 8; ++i)
            wpq[dst + i] = f2bf_rne(Wp[(size_t)(kb * 32 + gg * 8 + i) * 256 + col]);
    }
}

// ---------------------------------------------------------------------------
// Kernel 1: fused embeddings + parent projection via MFMA, 32 rows/block.
// 4 waves; wave w builds rows {8w..8w+7} of the bf16 emb tile, then computes
// two 16x64 D tiles (rows 0-15 / 16-31, cols 64w..64w+63) sharing B frags.
// ---------------------------------------------------------------------------
__global__ __launch_bounds__(256, 4) void emb_mfma_kernel(
    const int* __restrict__ node_type, const int* __restrict__ node_tokens,
    const float* __restrict__ type_table, const float* __restrict__ token_table,
    const unsigned short* __restrict__ wpq,   // packed W_parent
    const float* __restrict__ bp,
    float* __restrict__ out)
{
    constexpr int AP = 264;                   // padded stride (bf16 elems)
    __shared__ unsigned short A[CQ][AP];      // 16.5 KB

    const int tid  = threadIdx.x;
    const int lane = tid & 63;
    const int w    = tid >> 6;
    const int g0   = blockIdx.x * CQ;

    // phase 1: build bf16 emb tile
    #pragma unroll
    for (int it = 0; it < 8; ++it) {
        const int r = w * 8 + it;
        const int gnode = g0 + r;
        if (lane < 32) {
            const int tt = node_type[gnode];
            const float4 v = *reinterpret_cast<const float4*>(
                type_table + (size_t)tt * 128 + lane * 4);
            u16x4 s;
            s.x = f2bf_rne(v.x); s.y = f2bf_rne(v.y);
            s.z = f2bf_rne(v.z); s.w = f2bf_rne(v.w);
            *reinterpret_cast<u16x4*>(&A[r][lane * 4]) = s;
        } else {
            const int q = lane - 32;
            float4 acc = {0.f, 0.f, 0.f, 0.f};
            #pragma unroll
            for (int si = 0; si < Ss; ++si) {
                const int tok = node_tokens[gnode * Ss + si];
                const float4 v = *reinterpret_cast<const float4*>(
                    token_table + (size_t)tok * 128 + q * 4);
                acc.x += v.x; acc.y += v.y; acc.z += v.z; acc.w += v.w;
            }
            u16x4 s;
            s.x = f2bf_rne(acc.x); s.y = f2bf_rne(acc.y);
            s.z = f2bf_rne(acc.z); s.w = f2bf_rne(acc.w);
            *reinterpret_cast<u16x4*>(&A[r][128 + q * 4]) = s;
        }
    }
    __syncthreads();

    // phase 2: MFMA GEMM [32 x 256] @ [256 x 256], 2-deep B pipeline
    const int colg = w * 64;
    const int rr   = lane & 15;
    const int g    = lane >> 4;

    const unsigned short* pwh = wpq + ((size_t)(g * 256 + colg + rr)) * 8;

    f32x4 acc[2][4];
    #pragma unroll
    for (int t = 0; t < 2; ++t)
        #pragma unroll
        for (int f = 0; f < 4; ++f) acc[t][f] = (f32x4){0.f, 0.f, 0.f, 0.f};

    bf16x8 bA[4], bB[4];
    #pragma unroll
    for (int f = 0; f < 4; ++f)
        bA[f] = *reinterpret_cast<const bf16x8*>(pwh + f * 128);

    for (int kb = 0; kb < 8; kb += 2) {
        {
            const int o1 = (kb + 1) * 8192;
            #pragma unroll
            for (int f = 0; f < 4; ++f)
                bB[f] = *reinterpret_cast<const bf16x8*>(pwh + o1 + f * 128);
        }
        {
            const int k0 = kb * 32 + g * 8;
            const bf16x8 a0 = *reinterpret_cast<const bf16x8*>(&A[rr][k0]);
            const bf16x8 a1 = *reinterpret_cast<const bf16x8*>(&A[16 + rr][k0]);
            #pragma unroll
            for (int f = 0; f < 4; ++f) {
                acc[0][f] = __builtin_amdgcn_mfma_f32_16x16x32_bf16(a0, bA[f], acc[0][f], 0, 0, 0);
                acc[1][f] = __builtin_amdgcn_mfma_f32_16x16x32_bf16(a1, bA[f], acc[1][f], 0, 0, 0);
            }
        }
        if (kb + 2 < 8) {
            const int o2 = (kb + 2) * 8192;
            #pragma unroll
            for (int f = 0; f < 4; ++f)
                bA[f] = *reinterpret_cast<const bf16x8*>(pwh + o2 + f * 128);
        }
        {
            const int k0 = (kb + 1) * 32 + g * 8;
            const bf16x8 a0 = *reinterpret_cast<const bf16x8*>(&A[rr][k0]);
            const bf16x8 a1 = *reinterpret_cast<const bf16x8*>(&A[16 + rr][k0]);
            #pragma unroll
            for (int f = 0; f < 4; ++f) {
                acc[0][f] = __builtin_amdgcn_mfma_f32_16x16x32_bf16(a0, bB[f], acc[0][f], 0, 0, 0);
                acc[1][f] = __builtin_amdgcn_mfma_f32_16x16x32_bf16(a1, bB[f], acc[1][f], 0, 0, 0);
            }
        }
    }

    // epilogue: D row = t*16 + g*4+i, col = colg + f*16 + rr
    #pragma unroll
    for (int t = 0; t < 2; ++t)
        #pragma unroll
        for (int f = 0; f < 4; ++f) {
            const int col = colg + f * 16 + rr;
            const float bv = bp[col];
            #pragma unroll
            for (int i = 0; i < 4; ++i) {
                const int row = t * 16 + g * 4 + i;
                out[(size_t)(g0 + row) * 256 + col] = acc[t][f][i] + bv;
            }
        }
}

// ---------------------------------------------------------------------------
// Kernel 2: tree-conv layer, pure-bf16 MFMA, 32 rows/block, 4 waves.
// FUSE=1 (layer 2): epilogue additionally computes attention score, masked
// sigmoid weight, and the block's weighted column-sum -> partial[blk][256].
// ---------------------------------------------------------------------------
template<int FUSE>
__global__ __launch_bounds__(256, 3) void conv_mfma_kernel(
    const float* __restrict__ in_nodes,
    const int* __restrict__ children_index,
    const unsigned short* __restrict__ whi,   // layer offset pre-applied
    const float* __restrict__ bias,           // [256]
    float* __restrict__ out_nodes,
    const int* __restrict__ node_type,        // FUSE only
    const float* __restrict__ attn_a,         // FUSE only
    float* __restrict__ partial)              // FUSE only: [512][256]
{
    constexpr int AP = 776;                   // padded k-stride (bf16 elems)
    __shared__ unsigned short Ahi[CQ][AP];    // 48.5 KB
    __shared__ unsigned short idx_s[CQ][Cc];  // 1 KB
    __shared__ __half eta_s[2][CQ][Cc];       // 2 KB
    __shared__ float sc_lds[4][CQ];           // 0.5 KB (FUSE)
    __shared__ float wm_lds[CQ];              // 0.125 KB (FUSE)

    const int tid = threadIdx.x;

    // XCD swizzle: 32 blocks per batch; batch b -> XCD b%8.
    // P = (b%8) + 8*j + 256*(b/8), j<32
    const int P = blockIdx.x;
    const int xx = P & 7;
    const int rst = P >> 3;
    const int j = rst & 31;
    const int yy = rst >> 5;
    const int batch = xx + 8 * yy;
    const int g0 = batch * Nn + j * CQ;
    const float* inb = in_nodes + (size_t)batch * Nn * 256;

    // phase 1: children indices + TBCNN coefficients
    #pragma unroll
    for (int h = 0; h < 2; ++h) {
        const int r = h * 16 + (tid >> 4), c = tid & 15;
        idx_s[r][c] = (unsigned short)children_index[(size_t)(g0 + r) * Cc + c];
    }
    __syncthreads();
    #pragma unroll
    for (int h = 0; h < 2; ++h) {
        const int r = h * 16 + (tid >> 4), c = tid & 15;
        int ns = 0;
        #pragma unroll
        for (int q = 0; q < Cc; ++q) ns += (idx_s[r][q] > 0) ? 1 : 0;
        const bool cm = idx_s[r][c] > 0;
        float er;
        if (ns == 1) {
            er = (c == 0) ? 0.5f : 0.f;       // reference's "singles" quirk
        } else {
            const float denom = (float)((ns - 1 > 1) ? (ns - 1) : 1);
            er = (float)c / denom;
        }
        eta_s[0][r][c] = __float2half(cm ? er : 0.f);
        eta_s[1][r][c] = __float2half(cm ? (1.f - er) : 0.f);
    }
    __syncthreads();

    // phase 2: float4 gather + mix -> bf16 LDS tile [32][768]
    {
        const int q = tid & 63;               // float4 chunk within row
        const int rgrp = tid >> 6;            // wave id
        #pragma unroll
        for (int rr8 = 0; rr8 < 8; ++rr8) {
            const int r = rgrp + rr8 * 4;
            const float4 m0 = *reinterpret_cast<const float4*>(
                in_nodes + (size_t)(g0 + r) * 256 + q * 4);
            float4 m1 = {0.f, 0.f, 0.f, 0.f};
            float4 m2 = {0.f, 0.f, 0.f, 0.f};
            #pragma unroll
            for (int c = 0; c < Cc; ++c) {
                const int ci = idx_s[r][c];
                const float4 v = *reinterpret_cast<const float4*>(
                    inb + (size_t)ci * 256 + q * 4);
                const float er = __half2float(eta_s[0][r][c]);
                const float el = __half2float(eta_s[1][r][c]);
                m1.x = fmaf(er, v.x, m1.x); m1.y = fmaf(er, v.y, m1.y);
                m1.z = fmaf(er, v.z, m1.z); m1.w = fmaf(er, v.w, m1.w);
                m2.x = fmaf(el, v.x, m2.x); m2.y = fmaf(el, v.y, m2.y);
                m2.z = fmaf(el, v.z, m2.z); m2.w = fmaf(el, v.w, m2.w);
            }
            u16x4 s0, s1, s2;
            s0.x = f2bf_rne(m0.x); s0.y = f2bf_rne(m0.y);
            s0.z = f2bf_rne(m0.z); s0.w = f2bf_rne(m0.w);
            s1.x = f2bf_rne(m1.x); s1.y = f2bf_rne(m1.y);
            s1.z = f2bf_rne(m1.z); s1.w = f2bf_rne(m1.w);
            s2.x = f2bf_rne(m2.x); s2.y = f2bf_rne(m2.y);
            s2.z = f2bf_rne(m2.z); s2.w = f2bf_rne(m2.w);
            *reinterpret_cast<u16x4*>(&Ahi[r][q * 4])       = s0;
            *reinterpret_cast<u16x4*>(&Ahi[r][256 + q * 4]) = s1;
            *reinterpret_cast<u16x4*>(&Ahi[r][512 + q * 4]) = s2;
        }
    }
    __syncthreads();

    // phase 3: MFMA GEMM [32 x 768] @ [768 x 256], 2-deep B pipeline
    const int lane = tid & 63;
    const int w    = tid >> 6;
    const int colg = w * 64;
    const int rr   = lane & 15;               // A row-in-tile / D col-within-16
    const int g    = lane >> 4;               // k-subgroup / D row-group

    const unsigned short* pwh = whi + ((size_t)(g * 256 + colg + rr)) * 8;

    f32x4 acc[2][4];
    #pragma unroll
    for (int t = 0; t < 2; ++t)
        #pragma unroll
        for (int f = 0; f < 4; ++f) acc[t][f] = (f32x4){0.f, 0.f, 0.f, 0.f};

    bf16x8 bA[4], bB[4];
    #pragma unroll
    for (int f = 0; f < 4; ++f)
        bA[f] = *reinterpret_cast<const bf16x8*>(pwh + f * 128);

    for (int kb = 0; kb < 24; kb += 2) {
        {
            const int o1 = (kb + 1) * 8192;
            #pragma unroll
            for (int f = 0; f < 4; ++f)
                bB[f] = *reinterpret_cast<const bf16x8*>(pwh + o1 + f * 128);
        }
        {
            const int k0 = kb * 32 + g * 8;
            const bf16x8 a0 = *reinterpret_cast<const bf16x8*>(&Ahi[rr][k0]);
            const bf16x8 a1 = *reinterpret_cast<const bf16x8*>(&Ahi[16 + rr][k0]);
            #pragma unroll
            for (int f = 0; f < 4; ++f) {
                acc[0][f] = __builtin_amdgcn_mfma_f32_16x16x32_bf16(a0, bA[f], acc[0][f], 0, 0, 0);
                acc[1][f] = __builtin_amdgcn_mfma_f32_16x16x32_bf16(a1, bA[f], acc[1][f], 0, 0, 0);
            }
        }
        if (kb + 2 < 24) {
            const int o2 = (kb + 2) * 8192;
            #pragma unroll
            for (int f = 0; f < 4; ++f)
                bA[f] = *reinterpret_cast<const bf16x8*>(pwh + o2 + f * 128);
        }
        {
            const int k0 = (kb + 1) * 32 + g * 8;
            const bf16x8 a0 = *reinterpret_cast<const bf16x8*>(&Ahi[rr][k0]);
            const bf16x8 a1 = *reinterpret_cast<const bf16x8*>(&Ahi[16 + rr][k0]);
            #pragma unroll
            for (int f = 0; f < 4; ++f) {
                acc[0][f] = __builtin_amdgcn_mfma_f32_16x16x32_bf16(a0, bB[f], acc[0][f], 0, 0, 0);
                acc[1][f] = __builtin_amdgcn_mfma_f32_16x16x32_bf16(a1, bB[f], acc[1][f], 0, 0, 0);
            }
        }
    }

    // epilogue: D row = t*16 + g*4+i, col = colg + f*16 + rr
    float nd[2][4][4];
    #pragma unroll
    for (int t = 0; t < 2; ++t)
        #pragma unroll
        for (int f = 0; f < 4; ++f) {
            const int col = colg + f * 16 + rr;
            const float bv = bias[col];
            #pragma unroll
            for (int i = 0; i < 4; ++i) {
                const int row = t * 16 + g * 4 + i;
                const float v = tanhf(acc[t][f][i] + bv);
                nd[t][f][i] = v;
                out_nodes[(size_t)(g0 + row) * 256 + col] = v;
            }
        }

    if (FUSE) {
        // --- attention score: per-row dot(nodes_row, a) ---
        float av[4];
        #pragma unroll
        for (int f = 0; f < 4; ++f) av[f] = attn_a[colg + f * 16 + rr];

        float s[2][4];
        #pragma unroll
        for (int t = 0; t < 2; ++t)
            #pragma unroll
            for (int i = 0; i < 4; ++i) {
                float v = 0.f;
                #pragma unroll
                for (int f = 0; f < 4; ++f) v = fmaf(nd[t][f][i], av[f], v);
                s[t][i] = v;
            }
        // reduce across the 16 rr-lanes (covers the wave's 64 cols)
        #pragma unroll
        for (int off = 1; off < 16; off <<= 1)
            #pragma unroll
            for (int t = 0; t < 2; ++t)
                #pragma unroll
                for (int i = 0; i < 4; ++i)
                    s[t][i] += __shfl_xor(s[t][i], off, 64);
        if (rr == 0) {
            #pragma unroll
            for (int t = 0; t < 2; ++t)
                #pragma unroll
                for (int i = 0; i < 4; ++i)
                    sc_lds[w][t * 16 + g * 4 + i] = s[t][i];
        }
        __syncthreads();
        if (tid < CQ) {
            const float sc = sc_lds[0][tid] + sc_lds[1][tid] + sc_lds[2][tid] + sc_lds[3][tid];
            float wmv = 0.f;
            if (node_type[g0 + tid] != 0) wmv = 1.f / (1.f + expf(-sc));
            wm_lds[tid] = wmv;
        }
        __syncthreads();

        // --- weighted column-sum over the block's 32 rows ---
        float qf[4];
        #pragma unroll
        for (int f = 0; f < 4; ++f) {
            float v = 0.f;
            #pragma unroll
            for (int t = 0; t < 2; ++t)
                #pragma unroll
                for (int i = 0; i < 4; ++i)
                    v = fmaf(wm_lds[t * 16 + g * 4 + i], nd[t][f][i], v);
            qf[f] = v;
        }
        #pragma unroll
        for (int f = 0; f < 4; ++f) {
            qf[f] += __shfl_xor(qf[f], 16, 64);
            qf[f] += __shfl_xor(qf[f], 32, 64);
        }
        if (g == 0) {
            const int pidx = batch * 32 + j;
            #pragma unroll
            for (int f = 0; f < 4; ++f)
                partial[(size_t)pidx * 256 + colg + f * 16 + rr] = qf[f];
        }
    }
}

// ---------------------------------------------------------------------------
// Kernel 3: final reduce -> code_vector [16][256]
// ---------------------------------------------------------------------------
__global__ __launch_bounds__(256) void final_kernel(
    const float* __restrict__ partial, float* __restrict__ code)
{
    const int i = blockIdx.x * 256 + threadIdx.x;  // 0..4095
    const int b = i >> 8, o = i & 255;
    float acc = 0.f;
    #pragma unroll
    for (int c = 0; c < 32; ++c) acc += partial[(size_t)(b * 32 + c) * 256 + o];
    code[i] = acc * (1.f / 1024.f);
}

// ---------------------------------------------------------------------------
extern "C" void kernel_launch(void* const* d_in, const int* in_sizes, int n_in,
                              void* d_out, int out_size, void* d_ws, size_t ws_size,
                              hipStream_t stream)
{
    const int*   node_type   = (const int*)d_in[0];
    const int*   node_tokens = (const int*)d_in[1];
    const int*   children    = (const int*)d_in[2];
    const float* type_table  = (const float*)d_in[3];
    const float* token_table = (const float*)d_in[4];
    const float* Wp          = (const float*)d_in[5];
    const float* bp          = (const float*)d_in[6];
    const float* conv_w      = (const float*)d_in[7];
    const float* conv_b      = (const float*)d_in[8];
    const float* attn_a      = (const float*)d_in[9];

    float* out    = (float*)d_out;
    float* code   = out;                  // [B*O] = 4096
    float* nodesA = out + 4096;           // [BN*256]  (final nodes output)

    float* ws      = (float*)d_ws;
    float* nodesB  = ws;                      // [BN*256]
    float* partial = ws + (size_t)BN * 256;   // [512*256]
    unsigned short* whi = (unsigned short*)(partial + 512 * 256);  // [2][196608]
    unsigned short* wpq = whi + 2 * 196608;   // [65536]

    constexpr int LSTRIDE = 196608;           // packed shorts per layer

    pack_all_kernel<<<224, 256, 0, stream>>>(conv_w, Wp, whi, wpq);

    emb_mfma_kernel<<<BN / CQ, 256, 0, stream>>>(
        node_type, node_tokens, type_table, token_table, wpq, bp, nodesA);

    conv_mfma_kernel<0><<<BN / CQ, 256, 0, stream>>>(
        nodesA, children, whi, conv_b, nodesB,
        nullptr, nullptr, nullptr);

    conv_mfma_kernel<1><<<BN / CQ, 256, 0, stream>>>(
        nodesB, children, whi + LSTRIDE, conv_b + 256, nodesA,
        node_type, attn_a, partial);

    final_kernel<<<16, 256, 0, stream>>>(partial, code);
}